// Round 17
// baseline (101.038 us; speedup 1.0000x reference)
//
#include <hip/hip_runtime.h>
#include <stdint.h>

// Problem constants
#define B_   4
#define T_   2048
#define D_   512
#define H_   8
#define HS_  64

typedef __attribute__((ext_vector_type(8))) short bf16x8;
typedef __attribute__((ext_vector_type(4))) float f32x4;

__device__ __forceinline__ unsigned short f2bf(float f) {
  union { float f; unsigned u; } v; v.f = f;
  unsigned r = v.u + 0x7fffu + ((v.u >> 16) & 1u);   // RNE
  return (unsigned short)(r >> 16);
}

__device__ __forceinline__ void gload_lds16(const void* g, void* l) {
  __builtin_amdgcn_global_load_lds(
      (const __attribute__((address_space(1))) void*)g,
      (__attribute__((address_space(3))) void*)l,
      16, 0, 0);
}

// ---------------- fused prep: cast x, repack Wqkv, transpose Wo -------------
__global__ __launch_bounds__(256) void k_prep(
    const float* __restrict__ x,
    const float* __restrict__ Wq, const float* __restrict__ Wk,
    const float* __restrict__ Wv, const float* __restrict__ Wo,
    unsigned short* __restrict__ xb, unsigned short* __restrict__ Wtq,
    unsigned short* __restrict__ Wto)
{
  const int bid = blockIdx.x, tid = threadIdx.x;
  if (bid < 4096) {                                  // cast x: 4 floats/thread
    const int i = bid * 256 + tid;
    float4 v = ((const float4*)x)[i];
    ushort4 o;
    o.x = f2bf(v.x); o.y = f2bf(v.y); o.z = f2bf(v.z); o.w = f2bf(v.w);
    ((ushort4*)xb)[i] = o;
  } else if (bid < 7168) {                           // Wt[n][d] = Wproj[h][d][e]
    const int idx = (bid - 4096) * 256 + tid;        // < 1536*512
    const int n = idx >> 9, d = idx & 511;
    const int proj = n >> 9, c = n & 511, h = c >> 6, e = c & 63;
    const float* W = (proj == 0) ? Wq : ((proj == 1) ? Wk : Wv);
    Wtq[idx] = f2bf(W[((h << 9) + d) * 64 + e]);
  } else {                                           // Wot[n][d] = Wo[d][n]
    const int idx = (bid - 7168) * 256 + tid;        // < 512*512
    const int n = idx >> 9, d = idx & 511;
    Wto[idx] = f2bf(Wo[(d << 9) + n]);
  }
}

// ---------------- GEMM: C[M][N] = A[M][512] * Bt[N][512]^T ----------------
// R12/R13-proven form: 2-barrier BK=32 loop.
// MODE 0: scatter bf16 into Qb [B,H,T,64] (pre-scaled by HS^-0.5*log2e),
//         Kb [B,H,T,64], Vp [B,H,64,T] k-permuted; V packed ushort4 stores.
// MODE 1: fp32 out + bias into Cout [M][512]
template<int MODE>
__global__ __launch_bounds__(256) void k_gemm(
    const unsigned short* __restrict__ A, const unsigned short* __restrict__ Bt,
    unsigned short* __restrict__ Qb, unsigned short* __restrict__ Kb,
    unsigned short* __restrict__ Vp,
    const float* __restrict__ bo, float* __restrict__ Cout)
{
  const int m0 = blockIdx.y * 128, n0 = blockIdx.x * 128;
  __shared__ unsigned short At[128 * 32];
  __shared__ unsigned short Bs[128 * 32];
  const int tid = threadIdx.x, lane = tid & 63, wid = tid >> 6;
  const int wm = wid >> 1, wn = wid & 1;
  const int r16 = lane & 15, g = lane >> 4;

  f32x4 acc[4][4];
  const f32x4 fz = {0.f, 0.f, 0.f, 0.f};
#pragma unroll
  for (int i = 0; i < 4; ++i)
#pragma unroll
    for (int j = 0; j < 4; ++j) acc[i][j] = fz;

  for (int k0 = 0; k0 < 512; k0 += 32) {
#pragma unroll
    for (int j = 0; j < 2; ++j) {
      const int idx = j * 256 + tid;
      const int rr = idx >> 2, cc = (idx & 3) << 3;
      gload_lds16(A + (size_t)(m0 + rr) * 512 + k0 + cc, &At[(j * 256 + wid * 64) * 8]);
      gload_lds16(Bt + (size_t)(n0 + rr) * 512 + k0 + cc, &Bs[(j * 256 + wid * 64) * 8]);
    }
    __syncthreads();
    bf16x8 am[4], bn[4];
#pragma unroll
    for (int mi = 0; mi < 4; ++mi)
      am[mi] = *(const bf16x8*)&At[(wm * 64 + mi * 16 + r16) * 32 + g * 8];
#pragma unroll
    for (int ni = 0; ni < 4; ++ni)
      bn[ni] = *(const bf16x8*)&Bs[(wn * 64 + ni * 16 + r16) * 32 + g * 8];
#pragma unroll
    for (int mi = 0; mi < 4; ++mi)
#pragma unroll
      for (int ni = 0; ni < 4; ++ni)
        acc[mi][ni] = __builtin_amdgcn_mfma_f32_16x16x32_bf16(am[mi], bn[ni], acc[mi][ni], 0, 0, 0);
    __syncthreads();
  }

  const float QSC = 0.18033688f;                     // HS^-0.5 * log2(e)
#pragma unroll
  for (int mi = 0; mi < 4; ++mi) {
#pragma unroll
    for (int ni = 0; ni < 4; ++ni) {
      if (MODE == 0) {
        const int n = n0 + wn * 64 + ni * 16 + r16;
        const int proj = n >> 9, c = n & 511, h = c >> 6, e = c & 63;
        const int mbase = m0 + wm * 64 + mi * 16 + g * 4;   // + r, r=0..3
        const int b = mbase >> 11;
        if (proj == 2) {
          const int t0 = mbase & 2047;
          const int tblk = t0 >> 5;
          const int j0 = (g << 3) + ((mi & 1) << 2);
          ushort4 pv;
          pv.x = f2bf(acc[mi][ni][0]);
          pv.y = f2bf(acc[mi][ni][1]);
          pv.z = f2bf(acc[mi][ni][2]);
          pv.w = f2bf(acc[mi][ni][3]);
          *(ushort4*)&Vp[(((size_t)(b * 8 + h) << 6) + e) * 2048 + (tblk << 5) + j0] = pv;
        } else {
#pragma unroll
          for (int r = 0; r < 4; ++r) {
            const int m = mbase + r;
            const int t = m & 2047;
            const float val = acc[mi][ni][r];
            if (proj == 0)
              Qb[(((size_t)(b * 8 + h) * 2048 + t) << 6) + e] = f2bf(val * QSC);
            else
              Kb[(((size_t)(b * 8 + h) * 2048 + t) << 6) + e] = f2bf(val);
          }
        }
      } else {
#pragma unroll
        for (int r = 0; r < 4; ++r) {
          const int m = m0 + wm * 64 + mi * 16 + g * 4 + r;
          const int n = n0 + wn * 64 + ni * 16 + r16;
          Cout[(size_t)m * 512 + n] = acc[mi][ni][r] + bo[n];
        }
      }
    }
  }
}

// ---------------- flash attention (split-KV x2, 2 q-sets/wave) --------------
// Per-wave structure byte-identical to R13/R16 (best, passing): 32 q-rows,
// 2 q-sets, drain schedule, builtin exp2 + "s_nop 1" cvt_pk (hazard fix).
// SPLIT-KV x2: grid 1024 = 4 blocks/CU = 4 independent wave-streams/SIMD
// (vs 2) with per-CU MFMA/VALU/LDS-read totals UNCHANGED — pure overlap gain
// (R14 showed 4 streams absorbed +10us of extra LDS work; here there is no
// extra work). No-shift softmax makes partials exactly combinable:
// out = (O0+O1)/(L0+L1); partials stored f32 (no precision risk).
#define DRAINBAR() do { \
    asm volatile("s_waitcnt vmcnt(0)" ::: "memory"); \
    __builtin_amdgcn_s_barrier(); \
    asm volatile("" ::: "memory"); } while (0)

__global__ __launch_bounds__(256, 4) void k_attn(
    const unsigned short* __restrict__ Qb, const unsigned short* __restrict__ Kb,
    const unsigned short* __restrict__ Vp, float* __restrict__ Opart,
    float* __restrict__ Lp)
{
  const int lin = blockIdx.x;                        // 0..1023
  const int xcd = lin & 7, slot = lin >> 3;          // heads pinned per XCD
  const int bh = xcd * 4 + (slot & 3);
  const int rest = slot >> 2;                        // 0..31
  const int z = rest & 1;                            // KV half
  const int qblk = rest >> 1;                        // 0..15

  const int tid = threadIdx.x, lane = tid & 63, wid = tid >> 6;
  const int q0 = qblk * 128 + wid * 32;
  const int r16 = lane & 15, g = lane >> 4;
  const int swz = r16 & 7;
  const int kvb = z << 10;                           // 0 or 1024
  const unsigned short* Qh = Qb + (size_t)bh * T_ * 64;
  const unsigned short* Kh = Kb + (size_t)bh * T_ * 64;
  const unsigned short* Vh = Vp + (size_t)bh * 64 * T_;

  __shared__ unsigned short Ks[2][4096];             // [64 rows][64 elems], swizzled
  __shared__ unsigned short Vs[2][4096];

  // Q as MFMA B-frag (pre-scaled): col = lane&15 = q-row, d = g*8+i
  const bf16x8 qa00 = *(const bf16x8*)&Qh[(size_t)(q0 + r16) * 64 + g * 8];
  const bf16x8 qa01 = *(const bf16x8*)&Qh[(size_t)(q0 + r16) * 64 + 32 + g * 8];
  const bf16x8 qa10 = *(const bf16x8*)&Qh[(size_t)(q0 + 16 + r16) * 64 + g * 8];
  const bf16x8 qa11 = *(const bf16x8*)&Qh[(size_t)(q0 + 16 + r16) * 64 + 32 + g * 8];

  const f32x4 fz = {0.f, 0.f, 0.f, 0.f};
  f32x4 accA[4], accB[4];                            // O^T per q-set
#pragma unroll
  for (int eb = 0; eb < 4; ++eb) { accA[eb] = fz; accB[eb] = fz; }
  f32x4 accLA = fz, accLB = fz;                      // row-sums via ones-MFMA

  bf16x8 onesv;
#pragma unroll
  for (int i = 0; i < 8; ++i) onesv[i] = (short)0x3F80;  // bf16 1.0

  // staging: lane writes 16B at LDS linear (wid*1024B + lane*16B) [+4096B]
  // row = wid*8 + (lane>>3) [+32]; chunk pos = lane&7; source chunk = pos ^ (row&7)
  const int sb = wid * 8 + (lane >> 3);
  const int ssc = (lane & 7) ^ (lane >> 3);
  const unsigned short* kg = Kh + (size_t)(kvb + sb) * 64 + ssc * 8;
  const unsigned short* vg = Vh + (size_t)sb * T_ + kvb + ssc * 8;

  auto stage = [&](const unsigned short* kgp, const unsigned short* vgp, int bf) {
    gload_lds16(kgp,                   &Ks[bf][wid * 512]);
    gload_lds16(kgp + 32 * 64,         &Ks[bf][2048 + wid * 512]);
    gload_lds16(vgp,                   &Vs[bf][wid * 512]);
    gload_lds16(vgp + (size_t)32 * T_, &Vs[bf][2048 + wid * 512]);
  };

  auto compute = [&](int bf) {
#pragma unroll
    for (int sub = 0; sub < 2; ++sub) {
      const int rb = (sub * 32 + r16) * 64;
      const int c0 = (g ^ swz) << 3;
      const bf16x8 kf00 = *(const bf16x8*)&Ks[bf][rb + c0];
      const bf16x8 kf01 = *(const bf16x8*)&Ks[bf][rb + (c0 ^ 32)];
      const bf16x8 kf10 = *(const bf16x8*)&Ks[bf][rb + 1024 + c0];
      const bf16x8 kf11 = *(const bf16x8*)&Ks[bf][rb + 1024 + (c0 ^ 32)];
      // q-set A
      f32x4 s0a = __builtin_amdgcn_mfma_f32_16x16x32_bf16(kf00, qa00, fz, 0, 0, 0);
      s0a = __builtin_amdgcn_mfma_f32_16x16x32_bf16(kf01, qa01, s0a, 0, 0, 0);
      f32x4 s1a = __builtin_amdgcn_mfma_f32_16x16x32_bf16(kf10, qa00, fz, 0, 0, 0);
      s1a = __builtin_amdgcn_mfma_f32_16x16x32_bf16(kf11, qa01, s1a, 0, 0, 0);
      // q-set B
      f32x4 s0b = __builtin_amdgcn_mfma_f32_16x16x32_bf16(kf00, qa10, fz, 0, 0, 0);
      s0b = __builtin_amdgcn_mfma_f32_16x16x32_bf16(kf01, qa11, s0b, 0, 0, 0);
      f32x4 s1b = __builtin_amdgcn_mfma_f32_16x16x32_bf16(kf10, qa10, fz, 0, 0, 0);
      s1b = __builtin_amdgcn_mfma_f32_16x16x32_bf16(kf11, qa11, s1b, 0, 0, 0);

      float pa[8], pb[8];
#pragma unroll
      for (int r = 0; r < 4; ++r) {
        pa[r]     = __builtin_amdgcn_exp2f(s0a[r]);
        pa[4 + r] = __builtin_amdgcn_exp2f(s1a[r]);
        pb[r]     = __builtin_amdgcn_exp2f(s0b[r]);
        pb[4 + r] = __builtin_amdgcn_exp2f(s1b[r]);
      }
      union { bf16x8 v; unsigned u[4]; } puA, puB;
#pragma unroll
      for (int i = 0; i < 4; ++i) {
        asm("s_nop 1\n\tv_cvt_pk_bf16_f32 %0, %1, %2"
            : "=v"(puA.u[i]) : "v"(pa[2 * i]), "v"(pa[2 * i + 1]));
        asm("s_nop 1\n\tv_cvt_pk_bf16_f32 %0, %1, %2"
            : "=v"(puB.u[i]) : "v"(pb[2 * i]), "v"(pb[2 * i + 1]));
      }

#pragma unroll
      for (int eb = 0; eb < 4; ++eb) {
        const bf16x8 vf = *(const bf16x8*)&Vs[bf][(eb * 16 + r16) * 64 + (c0 ^ (sub << 5))];
        accA[eb] = __builtin_amdgcn_mfma_f32_16x16x32_bf16(vf, puA.v, accA[eb], 0, 0, 0);
        accB[eb] = __builtin_amdgcn_mfma_f32_16x16x32_bf16(vf, puB.v, accB[eb], 0, 0, 0);
      }
      accLA = __builtin_amdgcn_mfma_f32_16x16x32_bf16(onesv, puA.v, accLA, 0, 0, 0);
      accLB = __builtin_amdgcn_mfma_f32_16x16x32_bf16(onesv, puB.v, accLB, 0, 0, 0);
    }
  };

  // prologue: tile 0 into buf0, full drain
  stage(kg, vg, 0); kg += 4096; vg += 64;
  DRAINBAR();

  // main: 16 tiles (1024 keys); one barrier per tile
#pragma unroll 1
  for (int t = 0; t < 16; t += 2) {
    stage(kg, vg, 1); kg += 4096; vg += 64;          // tile t+1 -> buf1
    compute(0);                                      // tile t   (buf0)
    DRAINBAR();
    if (t < 14) { stage(kg, vg, 0); kg += 4096; vg += 64; }  // tile t+2 -> buf0
    compute(1);                                      // tile t+1 (buf1)
    DRAINBAR();
  }

  // partials (unnormalized): Opart[z][bh][t][e], L[z][bh][t]
  const size_t rbA = ((size_t)(z * 32 + bh) * T_ + q0 + r16) * 64;
  const size_t rbB = rbA + (size_t)16 * 64;
#pragma unroll
  for (int eb = 0; eb < 4; ++eb) {
    *(f32x4*)&Opart[rbA + eb * 16 + g * 4] = accA[eb];
    *(f32x4*)&Opart[rbB + eb * 16 + g * 4] = accB[eb];
  }
  if (g == 0) {
    Lp[(size_t)(z * 32 + bh) * T_ + q0 + r16]      = accLA[0];
    Lp[(size_t)(z * 32 + bh) * T_ + q0 + 16 + r16] = accLB[0];
  }
}

// ---------------- combine split-KV partials -> Ob bf16 [B][T][D] ------------
// No-shift softmax => exact: out = (O0+O1)/(L0+L1). 4 elems/thread, f32x4.
__global__ __launch_bounds__(256) void k_combine(
    const float* __restrict__ Opart, const float* __restrict__ Lp,
    unsigned short* __restrict__ Ob)
{
  const int i4 = blockIdx.x * 256 + threadIdx.x;     // < 1048576
  const size_t base = (size_t)i4 * 4;
  const int e = (int)(base & 63), t = (int)((base >> 6) & 2047), bh = (int)(base >> 17);
  const float L = Lp[(size_t)bh * T_ + t] + Lp[(size_t)(32 + bh) * T_ + t];
  const float inv = 1.0f / L;
  const f32x4 o0 = *(const f32x4*)&Opart[base];
  const f32x4 o1 = *(const f32x4*)&Opart[4194304 + base];
  ushort4 ow;
  ow.x = f2bf((o0[0] + o1[0]) * inv);
  ow.y = f2bf((o0[1] + o1[1]) * inv);
  ow.z = f2bf((o0[2] + o1[2]) * inv);
  ow.w = f2bf((o0[3] + o1[3]) * inv);
  const int b = bh >> 3, h = bh & 7;
  *(ushort4*)&Ob[((size_t)(b * 2048 + t) << 9) + h * 64 + e] = ow;
}

// ---------------- launch ----------------
extern "C" void kernel_launch(void* const* d_in, const int* in_sizes, int n_in,
                              void* d_out, int out_size, void* d_ws, size_t ws_size,
                              hipStream_t stream) {
  const float* x  = (const float*)d_in[0];
  const float* Wq = (const float*)d_in[1];
  const float* Wk = (const float*)d_in[2];
  const float* Wv = (const float*)d_in[3];
  const float* Wo = (const float*)d_in[4];
  const float* bo = (const float*)d_in[5];
  float* out = (float*)d_out;
  char* ws = (char*)d_ws;

  unsigned short* xb  = (unsigned short*)(ws);                 // 8 MiB
  unsigned short* Wtq = (unsigned short*)(ws + 8388608);       // 1.5 MiB
  unsigned short* Wto = (unsigned short*)(ws + 9961472);       // 0.5 MiB
  unsigned short* Qb  = (unsigned short*)(ws + 10485760);      // 8 MiB
  unsigned short* Kb  = (unsigned short*)(ws + 18874368);      // 8 MiB
  unsigned short* Vp  = (unsigned short*)(ws + 27262976);      // 8 MiB
  unsigned short* Ob  = (unsigned short*)(ws + 35651584);      // 8 MiB
  float*          Opart = (float*)(ws + 44040192);             // 32 MiB (2 splits)
  float*          Lp    = (float*)(ws + 77594624);             // 0.5 MiB

  k_prep    <<<8192, 256, 0, stream>>>(x, Wq, Wk, Wv, Wo, xb, Wtq, Wto);
  k_gemm<0> <<<dim3(12, 64), 256, 0, stream>>>(xb, Wtq, Qb, Kb, Vp, nullptr, nullptr);
  k_attn    <<<1024, 256, 0, stream>>>(Qb, Kb, Vp, Opart, Lp);
  k_combine <<<4096, 256, 0, stream>>>(Opart, Lp, Ob);
  k_gemm<1> <<<dim3(4, 64), 256, 0, stream>>>(Ob, Wto, nullptr, nullptr, nullptr, bo, out);
}

// Round 18
// 95.019 us; speedup vs baseline: 1.0634x; 1.0634x over previous
//
#include <hip/hip_runtime.h>
#include <stdint.h>

// Problem constants
#define B_   4
#define T_   2048
#define D_   512
#define H_   8
#define HS_  64

typedef __attribute__((ext_vector_type(8))) short bf16x8;
typedef __attribute__((ext_vector_type(4))) float f32x4;

__device__ __forceinline__ unsigned short f2bf(float f) {
  union { float f; unsigned u; } v; v.f = f;
  unsigned r = v.u + 0x7fffu + ((v.u >> 16) & 1u);   // RNE
  return (unsigned short)(r >> 16);
}

__device__ __forceinline__ void gload_lds16(const void* g, void* l) {
  __builtin_amdgcn_global_load_lds(
      (const __attribute__((address_space(1))) void*)g,
      (__attribute__((address_space(3))) void*)l,
      16, 0, 0);
}

// ---------------- fused prep: cast x, repack Wqkv, transpose Wo -------------
__global__ __launch_bounds__(256) void k_prep(
    const float* __restrict__ x,
    const float* __restrict__ Wq, const float* __restrict__ Wk,
    const float* __restrict__ Wv, const float* __restrict__ Wo,
    unsigned short* __restrict__ xb, unsigned short* __restrict__ Wtq,
    unsigned short* __restrict__ Wto)
{
  const int bid = blockIdx.x, tid = threadIdx.x;
  if (bid < 4096) {                                  // cast x: 4 floats/thread
    const int i = bid * 256 + tid;
    float4 v = ((const float4*)x)[i];
    ushort4 o;
    o.x = f2bf(v.x); o.y = f2bf(v.y); o.z = f2bf(v.z); o.w = f2bf(v.w);
    ((ushort4*)xb)[i] = o;
  } else if (bid < 7168) {                           // Wt[n][d] = Wproj[h][d][e]
    const int idx = (bid - 4096) * 256 + tid;        // < 1536*512
    const int n = idx >> 9, d = idx & 511;
    const int proj = n >> 9, c = n & 511, h = c >> 6, e = c & 63;
    const float* W = (proj == 0) ? Wq : ((proj == 1) ? Wk : Wv);
    Wtq[idx] = f2bf(W[((h << 9) + d) * 64 + e]);
  } else {                                           // Wot[n][d] = Wo[d][n]
    const int idx = (bid - 7168) * 256 + tid;        // < 512*512
    const int n = idx >> 9, d = idx & 511;
    Wto[idx] = f2bf(Wo[(d << 9) + n]);
  }
}

// ---------------- GEMM: C[M][N] = A[M][512] * Bt[N][512]^T ----------------
// R12/R13-proven form: 2-barrier BK=32 loop (implicit wave overlap at
// 3 blocks/CU already hides staging — R15's 1-barrier restructure regressed).
// MODE 0: scatter bf16 into Qb [B,H,T,64] (pre-scaled by HS^-0.5*log2e),
//         Kb [B,H,T,64], Vp [B,H,64,T] k-permuted; V packed ushort4 stores.
// MODE 1: fp32 out + bias into Cout [M][512]
template<int MODE>
__global__ __launch_bounds__(256) void k_gemm(
    const unsigned short* __restrict__ A, const unsigned short* __restrict__ Bt,
    unsigned short* __restrict__ Qb, unsigned short* __restrict__ Kb,
    unsigned short* __restrict__ Vp,
    const float* __restrict__ bo, float* __restrict__ Cout)
{
  const int m0 = blockIdx.y * 128, n0 = blockIdx.x * 128;
  __shared__ unsigned short At[128 * 32];
  __shared__ unsigned short Bs[128 * 32];
  const int tid = threadIdx.x, lane = tid & 63, wid = tid >> 6;
  const int wm = wid >> 1, wn = wid & 1;
  const int r16 = lane & 15, g = lane >> 4;

  f32x4 acc[4][4];
  const f32x4 fz = {0.f, 0.f, 0.f, 0.f};
#pragma unroll
  for (int i = 0; i < 4; ++i)
#pragma unroll
    for (int j = 0; j < 4; ++j) acc[i][j] = fz;

  for (int k0 = 0; k0 < 512; k0 += 32) {
#pragma unroll
    for (int j = 0; j < 2; ++j) {
      const int idx = j * 256 + tid;
      const int rr = idx >> 2, cc = (idx & 3) << 3;
      gload_lds16(A + (size_t)(m0 + rr) * 512 + k0 + cc, &At[(j * 256 + wid * 64) * 8]);
      gload_lds16(Bt + (size_t)(n0 + rr) * 512 + k0 + cc, &Bs[(j * 256 + wid * 64) * 8]);
    }
    __syncthreads();
    bf16x8 am[4], bn[4];
#pragma unroll
    for (int mi = 0; mi < 4; ++mi)
      am[mi] = *(const bf16x8*)&At[(wm * 64 + mi * 16 + r16) * 32 + g * 8];
#pragma unroll
    for (int ni = 0; ni < 4; ++ni)
      bn[ni] = *(const bf16x8*)&Bs[(wn * 64 + ni * 16 + r16) * 32 + g * 8];
#pragma unroll
    for (int mi = 0; mi < 4; ++mi)
#pragma unroll
      for (int ni = 0; ni < 4; ++ni)
        acc[mi][ni] = __builtin_amdgcn_mfma_f32_16x16x32_bf16(am[mi], bn[ni], acc[mi][ni], 0, 0, 0);
    __syncthreads();
  }

  const float QSC = 0.18033688f;                     // HS^-0.5 * log2(e)
#pragma unroll
  for (int mi = 0; mi < 4; ++mi) {
#pragma unroll
    for (int ni = 0; ni < 4; ++ni) {
      if (MODE == 0) {
        const int n = n0 + wn * 64 + ni * 16 + r16;
        const int proj = n >> 9, c = n & 511, h = c >> 6, e = c & 63;
        const int mbase = m0 + wm * 64 + mi * 16 + g * 4;   // + r, r=0..3
        const int b = mbase >> 11;
        if (proj == 2) {
          const int t0 = mbase & 2047;
          const int tblk = t0 >> 5;
          const int j0 = (g << 3) + ((mi & 1) << 2);
          ushort4 pv;
          pv.x = f2bf(acc[mi][ni][0]);
          pv.y = f2bf(acc[mi][ni][1]);
          pv.z = f2bf(acc[mi][ni][2]);
          pv.w = f2bf(acc[mi][ni][3]);
          *(ushort4*)&Vp[(((size_t)(b * 8 + h) << 6) + e) * 2048 + (tblk << 5) + j0] = pv;
        } else {
#pragma unroll
          for (int r = 0; r < 4; ++r) {
            const int m = mbase + r;
            const int t = m & 2047;
            const float val = acc[mi][ni][r];
            if (proj == 0)
              Qb[(((size_t)(b * 8 + h) * 2048 + t) << 6) + e] = f2bf(val * QSC);
            else
              Kb[(((size_t)(b * 8 + h) * 2048 + t) << 6) + e] = f2bf(val);
          }
        }
      } else {
#pragma unroll
        for (int r = 0; r < 4; ++r) {
          const int m = m0 + wm * 64 + mi * 16 + g * 4 + r;
          const int n = n0 + wn * 64 + ni * 16 + r16;
          Cout[(size_t)m * 512 + n] = acc[mi][ni][r] + bo[n];
        }
      }
    }
  }
}

// ---------------- flash attention (LDS-staged K/V, 2 q-sets/wave) -----------
// R13/R16 exactly (best: 45.3us attn, 95.07us total, passing). Drain
// schedule (one barrier/tile, vmcnt(0) robust), (256,3), builtin exp2 +
// "s_nop 1" inside cvt_pk asm (trans-use hazard protection — root cause of
// R7/R10/R11 failures), ones-MFMA L, XCD head-pinning. No setprio (R15 −3us),
// no split-KV (R17: attn −2.7us but combine +8.6us = net loss), no 16-row
// waves (R14 +1.4us). This configuration is the measured fixed point of the
// structure across five variants.
#define DRAINBAR() do { \
    asm volatile("s_waitcnt vmcnt(0)" ::: "memory"); \
    __builtin_amdgcn_s_barrier(); \
    asm volatile("" ::: "memory"); } while (0)

__global__ __launch_bounds__(256, 3) void k_attn(
    const unsigned short* __restrict__ Qb, const unsigned short* __restrict__ Kb,
    const unsigned short* __restrict__ Vp, unsigned short* __restrict__ Ob)
{
  const int lin = blockIdx.x;                        // 0..511
  const int xcd = lin & 7, slot = lin >> 3;          // heads pinned per XCD
  const int bh = xcd * 4 + (slot & 3);
  const int qblk = slot >> 2;                        // 0..15
  const int b = bh >> 3, h = bh & 7;

  const int tid = threadIdx.x, lane = tid & 63, wid = tid >> 6;
  const int q0 = qblk * 128 + wid * 32;
  const int r16 = lane & 15, g = lane >> 4;
  const int swz = r16 & 7;
  const unsigned short* Qh = Qb + (size_t)bh * T_ * 64;
  const unsigned short* Kh = Kb + (size_t)bh * T_ * 64;
  const unsigned short* Vh = Vp + (size_t)bh * 64 * T_;

  __shared__ unsigned short Ks[2][4096];             // [64 rows][64 elems], swizzled
  __shared__ unsigned short Vs[2][4096];

  // Q as MFMA B-frag (pre-scaled): col = lane&15 = q-row, d = g*8+i
  const bf16x8 qa00 = *(const bf16x8*)&Qh[(size_t)(q0 + r16) * 64 + g * 8];
  const bf16x8 qa01 = *(const bf16x8*)&Qh[(size_t)(q0 + r16) * 64 + 32 + g * 8];
  const bf16x8 qa10 = *(const bf16x8*)&Qh[(size_t)(q0 + 16 + r16) * 64 + g * 8];
  const bf16x8 qa11 = *(const bf16x8*)&Qh[(size_t)(q0 + 16 + r16) * 64 + 32 + g * 8];

  const f32x4 fz = {0.f, 0.f, 0.f, 0.f};
  f32x4 accA[4], accB[4];                            // O^T per q-set
#pragma unroll
  for (int eb = 0; eb < 4; ++eb) { accA[eb] = fz; accB[eb] = fz; }
  f32x4 accLA = fz, accLB = fz;                      // row-sums via ones-MFMA

  bf16x8 onesv;
#pragma unroll
  for (int i = 0; i < 8; ++i) onesv[i] = (short)0x3F80;  // bf16 1.0

  // staging: lane writes 16B at LDS linear (wid*1024B + lane*16B) [+4096B]
  // row = wid*8 + (lane>>3) [+32]; chunk pos = lane&7; source chunk = pos ^ (row&7)
  const int sb = wid * 8 + (lane >> 3);
  const int ssc = (lane & 7) ^ (lane >> 3);
  const unsigned short* kg = Kh + (size_t)sb * 64 + ssc * 8;
  const unsigned short* vg = Vh + (size_t)sb * T_ + ssc * 8;

  auto stage = [&](const unsigned short* kgp, const unsigned short* vgp, int bf) {
    gload_lds16(kgp,                   &Ks[bf][wid * 512]);
    gload_lds16(kgp + 32 * 64,         &Ks[bf][2048 + wid * 512]);
    gload_lds16(vgp,                   &Vs[bf][wid * 512]);
    gload_lds16(vgp + (size_t)32 * T_, &Vs[bf][2048 + wid * 512]);
  };

  auto compute = [&](int bf) {
#pragma unroll
    for (int sub = 0; sub < 2; ++sub) {
      const int rb = (sub * 32 + r16) * 64;
      const int c0 = (g ^ swz) << 3;
      const bf16x8 kf00 = *(const bf16x8*)&Ks[bf][rb + c0];
      const bf16x8 kf01 = *(const bf16x8*)&Ks[bf][rb + (c0 ^ 32)];
      const bf16x8 kf10 = *(const bf16x8*)&Ks[bf][rb + 1024 + c0];
      const bf16x8 kf11 = *(const bf16x8*)&Ks[bf][rb + 1024 + (c0 ^ 32)];
      // q-set A
      f32x4 s0a = __builtin_amdgcn_mfma_f32_16x16x32_bf16(kf00, qa00, fz, 0, 0, 0);
      s0a = __builtin_amdgcn_mfma_f32_16x16x32_bf16(kf01, qa01, s0a, 0, 0, 0);
      f32x4 s1a = __builtin_amdgcn_mfma_f32_16x16x32_bf16(kf10, qa00, fz, 0, 0, 0);
      s1a = __builtin_amdgcn_mfma_f32_16x16x32_bf16(kf11, qa01, s1a, 0, 0, 0);
      // q-set B
      f32x4 s0b = __builtin_amdgcn_mfma_f32_16x16x32_bf16(kf00, qa10, fz, 0, 0, 0);
      s0b = __builtin_amdgcn_mfma_f32_16x16x32_bf16(kf01, qa11, s0b, 0, 0, 0);
      f32x4 s1b = __builtin_amdgcn_mfma_f32_16x16x32_bf16(kf10, qa10, fz, 0, 0, 0);
      s1b = __builtin_amdgcn_mfma_f32_16x16x32_bf16(kf11, qa11, s1b, 0, 0, 0);

      float pa[8], pb[8];
#pragma unroll
      for (int r = 0; r < 4; ++r) {
        pa[r]     = __builtin_amdgcn_exp2f(s0a[r]);
        pa[4 + r] = __builtin_amdgcn_exp2f(s1a[r]);
        pb[r]     = __builtin_amdgcn_exp2f(s0b[r]);
        pb[4 + r] = __builtin_amdgcn_exp2f(s1b[r]);
      }
      union { bf16x8 v; unsigned u[4]; } puA, puB;
#pragma unroll
      for (int i = 0; i < 4; ++i) {
        asm("s_nop 1\n\tv_cvt_pk_bf16_f32 %0, %1, %2"
            : "=v"(puA.u[i]) : "v"(pa[2 * i]), "v"(pa[2 * i + 1]));
        asm("s_nop 1\n\tv_cvt_pk_bf16_f32 %0, %1, %2"
            : "=v"(puB.u[i]) : "v"(pb[2 * i]), "v"(pb[2 * i + 1]));
      }

#pragma unroll
      for (int eb = 0; eb < 4; ++eb) {
        const bf16x8 vf = *(const bf16x8*)&Vs[bf][(eb * 16 + r16) * 64 + (c0 ^ (sub << 5))];
        accA[eb] = __builtin_amdgcn_mfma_f32_16x16x32_bf16(vf, puA.v, accA[eb], 0, 0, 0);
        accB[eb] = __builtin_amdgcn_mfma_f32_16x16x32_bf16(vf, puB.v, accB[eb], 0, 0, 0);
      }
      accLA = __builtin_amdgcn_mfma_f32_16x16x32_bf16(onesv, puA.v, accLA, 0, 0, 0);
      accLB = __builtin_amdgcn_mfma_f32_16x16x32_bf16(onesv, puB.v, accLB, 0, 0, 0);
    }
  };

  // prologue: tile 0 into buf0, full drain
  stage(kg, vg, 0); kg += 4096; vg += 64;
  DRAINBAR();

  // main: one barrier per tile; stage(t+1) flight hidden under compute(t)
#pragma unroll 1
  for (int t = 0; t < 32; t += 2) {
    stage(kg, vg, 1); kg += 4096; vg += 64;          // tile t+1 -> buf1
    compute(0);                                      // tile t   (buf0)
    DRAINBAR();
    if (t < 30) { stage(kg, vg, 0); kg += 4096; vg += 64; }  // tile t+2 -> buf0
    compute(1);                                      // tile t+1 (buf1)
    DRAINBAR();
  }

  const float invLA = 1.0f / accLA[0];
  const float invLB = 1.0f / accLB[0];
  unsigned short* OrowA = Ob + ((size_t)(b * 2048 + q0 + r16) << 9) + h * 64 + g * 4;
  unsigned short* OrowB = Ob + ((size_t)(b * 2048 + q0 + 16 + r16) << 9) + h * 64 + g * 4;
#pragma unroll
  for (int eb = 0; eb < 4; ++eb) {
    uint2 ow;
    asm("v_cvt_pk_bf16_f32 %0, %1, %2" : "=v"(ow.x)
        : "v"(accA[eb][0] * invLA), "v"(accA[eb][1] * invLA));
    asm("v_cvt_pk_bf16_f32 %0, %1, %2" : "=v"(ow.y)
        : "v"(accA[eb][2] * invLA), "v"(accA[eb][3] * invLA));
    *(uint2*)(OrowA + eb * 16) = ow;
    asm("v_cvt_pk_bf16_f32 %0, %1, %2" : "=v"(ow.x)
        : "v"(accB[eb][0] * invLB), "v"(accB[eb][1] * invLB));
    asm("v_cvt_pk_bf16_f32 %0, %1, %2" : "=v"(ow.y)
        : "v"(accB[eb][2] * invLB), "v"(accB[eb][3] * invLB));
    *(uint2*)(OrowB + eb * 16) = ow;
  }
}

// ---------------- launch ----------------
extern "C" void kernel_launch(void* const* d_in, const int* in_sizes, int n_in,
                              void* d_out, int out_size, void* d_ws, size_t ws_size,
                              hipStream_t stream) {
  const float* x  = (const float*)d_in[0];
  const float* Wq = (const float*)d_in[1];
  const float* Wk = (const float*)d_in[2];
  const float* Wv = (const float*)d_in[3];
  const float* Wo = (const float*)d_in[4];
  const float* bo = (const float*)d_in[5];
  float* out = (float*)d_out;
  char* ws = (char*)d_ws;

  unsigned short* xb  = (unsigned short*)(ws);                 // 8 MiB
  unsigned short* Wtq = (unsigned short*)(ws + 8388608);       // 1.5 MiB
  unsigned short* Wto = (unsigned short*)(ws + 9961472);       // 0.5 MiB
  unsigned short* Qb  = (unsigned short*)(ws + 10485760);      // 8 MiB
  unsigned short* Kb  = (unsigned short*)(ws + 18874368);      // 8 MiB
  unsigned short* Vp  = (unsigned short*)(ws + 27262976);      // 8 MiB
  unsigned short* Ob  = (unsigned short*)(ws + 35651584);      // 8 MiB

  k_prep    <<<8192, 256, 0, stream>>>(x, Wq, Wk, Wv, Wo, xb, Wtq, Wto);
  k_gemm<0> <<<dim3(12, 64), 256, 0, stream>>>(xb, Wtq, Qb, Kb, Vp, nullptr, nullptr);
  k_attn    <<<512, 256, 0, stream>>>(Qb, Kb, Vp, Ob);
  k_gemm<1> <<<dim3(4, 64), 256, 0, stream>>>(Ob, Wto, nullptr, nullptr, nullptr, bo, out);
}

// Round 19
// 93.214 us; speedup vs baseline: 1.0839x; 1.0194x over previous
//
#include <hip/hip_runtime.h>
#include <stdint.h>

// Problem constants
#define B_   4
#define T_   2048
#define D_   512
#define H_   8
#define HS_  64

typedef __attribute__((ext_vector_type(8))) short bf16x8;
typedef __attribute__((ext_vector_type(4))) float f32x4;

__device__ __forceinline__ unsigned short f2bf(float f) {
  union { float f; unsigned u; } v; v.f = f;
  unsigned r = v.u + 0x7fffu + ((v.u >> 16) & 1u);   // RNE
  return (unsigned short)(r >> 16);
}

__device__ __forceinline__ void gload_lds16(const void* g, void* l) {
  __builtin_amdgcn_global_load_lds(
      (const __attribute__((address_space(1))) void*)g,
      (__attribute__((address_space(3))) void*)l,
      16, 0, 0);
}

// ---------------- fused prep: cast x, repack Wqkv, transpose Wo -------------
__global__ __launch_bounds__(256) void k_prep(
    const float* __restrict__ x,
    const float* __restrict__ Wq, const float* __restrict__ Wk,
    const float* __restrict__ Wv, const float* __restrict__ Wo,
    unsigned short* __restrict__ xb, unsigned short* __restrict__ Wtq,
    unsigned short* __restrict__ Wto)
{
  const int bid = blockIdx.x, tid = threadIdx.x;
  if (bid < 4096) {                                  // cast x: 4 floats/thread
    const int i = bid * 256 + tid;
    float4 v = ((const float4*)x)[i];
    ushort4 o;
    o.x = f2bf(v.x); o.y = f2bf(v.y); o.z = f2bf(v.z); o.w = f2bf(v.w);
    ((ushort4*)xb)[i] = o;
  } else if (bid < 7168) {                           // Wt[n][d] = Wproj[h][d][e]
    const int idx = (bid - 4096) * 256 + tid;        // < 1536*512
    const int n = idx >> 9, d = idx & 511;
    const int proj = n >> 9, c = n & 511, h = c >> 6, e = c & 63;
    const float* W = (proj == 0) ? Wq : ((proj == 1) ? Wk : Wv);
    Wtq[idx] = f2bf(W[((h << 9) + d) * 64 + e]);
  } else {                                           // Wot[n][d] = Wo[d][n]
    const int idx = (bid - 7168) * 256 + tid;        // < 512*512
    const int n = idx >> 9, d = idx & 511;
    Wto[idx] = f2bf(Wo[(d << 9) + n]);
  }
}

// ---------------- GEMM: C[M][N] = A[M][512] * Bt[N][512]^T ----------------
// R12/R13-proven inner structure (2-barrier BK=32 loop) + NEW this round:
// XCD-aware bijective block swizzle (T1). Default x-fastest dispatch puts 8
// consecutive blocks (which share one 128-row A-panel) on 8 different XCDs;
// the chunked remap gives each XCD a contiguous work-id run so A-panels are
// reused within one XCD's L2. nwg%8==0 for both grids (768, 256) => bijective.
// MODE 0: scatter bf16 into Qb [B,H,T,64] (pre-scaled by HS^-0.5*log2e),
//         Kb [B,H,T,64], Vp [B,H,64,T] k-permuted; V packed ushort4 stores.
// MODE 1: fp32 out + bias into Cout [M][512]
template<int MODE>
__global__ __launch_bounds__(256) void k_gemm(
    const unsigned short* __restrict__ A, const unsigned short* __restrict__ Bt,
    unsigned short* __restrict__ Qb, unsigned short* __restrict__ Kb,
    unsigned short* __restrict__ Vp,
    const float* __restrict__ bo, float* __restrict__ Cout)
{
  // XCD-chunked bijective remap (nwg % 8 == 0)
  const int nwg = gridDim.x * gridDim.y;
  const int lin = blockIdx.y * gridDim.x + blockIdx.x;
  const int chunk = nwg >> 3;
  const int wk = (lin & 7) * chunk + (lin >> 3);
  const int m0 = (wk / gridDim.x) * 128, n0 = (wk % gridDim.x) * 128;

  __shared__ unsigned short At[128 * 32];
  __shared__ unsigned short Bs[128 * 32];
  const int tid = threadIdx.x, lane = tid & 63, wid = tid >> 6;
  const int wm = wid >> 1, wn = wid & 1;
  const int r16 = lane & 15, g = lane >> 4;

  f32x4 acc[4][4];
  const f32x4 fz = {0.f, 0.f, 0.f, 0.f};
#pragma unroll
  for (int i = 0; i < 4; ++i)
#pragma unroll
    for (int j = 0; j < 4; ++j) acc[i][j] = fz;

  for (int k0 = 0; k0 < 512; k0 += 32) {
#pragma unroll
    for (int j = 0; j < 2; ++j) {
      const int idx = j * 256 + tid;
      const int rr = idx >> 2, cc = (idx & 3) << 3;
      gload_lds16(A + (size_t)(m0 + rr) * 512 + k0 + cc, &At[(j * 256 + wid * 64) * 8]);
      gload_lds16(Bt + (size_t)(n0 + rr) * 512 + k0 + cc, &Bs[(j * 256 + wid * 64) * 8]);
    }
    __syncthreads();
    bf16x8 am[4], bn[4];
#pragma unroll
    for (int mi = 0; mi < 4; ++mi)
      am[mi] = *(const bf16x8*)&At[(wm * 64 + mi * 16 + r16) * 32 + g * 8];
#pragma unroll
    for (int ni = 0; ni < 4; ++ni)
      bn[ni] = *(const bf16x8*)&Bs[(wn * 64 + ni * 16 + r16) * 32 + g * 8];
#pragma unroll
    for (int mi = 0; mi < 4; ++mi)
#pragma unroll
      for (int ni = 0; ni < 4; ++ni)
        acc[mi][ni] = __builtin_amdgcn_mfma_f32_16x16x32_bf16(am[mi], bn[ni], acc[mi][ni], 0, 0, 0);
    __syncthreads();
  }

  const float QSC = 0.18033688f;                     // HS^-0.5 * log2(e)
#pragma unroll
  for (int mi = 0; mi < 4; ++mi) {
#pragma unroll
    for (int ni = 0; ni < 4; ++ni) {
      if (MODE == 0) {
        const int n = n0 + wn * 64 + ni * 16 + r16;
        const int proj = n >> 9, c = n & 511, h = c >> 6, e = c & 63;
        const int mbase = m0 + wm * 64 + mi * 16 + g * 4;   // + r, r=0..3
        const int b = mbase >> 11;
        if (proj == 2) {
          const int t0 = mbase & 2047;
          const int tblk = t0 >> 5;
          const int j0 = (g << 3) + ((mi & 1) << 2);
          ushort4 pv;
          pv.x = f2bf(acc[mi][ni][0]);
          pv.y = f2bf(acc[mi][ni][1]);
          pv.z = f2bf(acc[mi][ni][2]);
          pv.w = f2bf(acc[mi][ni][3]);
          *(ushort4*)&Vp[(((size_t)(b * 8 + h) << 6) + e) * 2048 + (tblk << 5) + j0] = pv;
        } else {
#pragma unroll
          for (int r = 0; r < 4; ++r) {
            const int m = mbase + r;
            const int t = m & 2047;
            const float val = acc[mi][ni][r];
            if (proj == 0)
              Qb[(((size_t)(b * 8 + h) * 2048 + t) << 6) + e] = f2bf(val * QSC);
            else
              Kb[(((size_t)(b * 8 + h) * 2048 + t) << 6) + e] = f2bf(val);
          }
        }
      } else {
#pragma unroll
        for (int r = 0; r < 4; ++r) {
          const int m = m0 + wm * 64 + mi * 16 + g * 4 + r;
          const int n = n0 + wn * 64 + ni * 16 + r16;
          Cout[(size_t)m * 512 + n] = acc[mi][ni][r] + bo[n];
        }
      }
    }
  }
}

// ---------------- flash attention (LDS-staged K/V, 2 q-sets/wave) -----------
// R13/R16 exactly (best: 45.3us attn, passing) — FROZEN. Drain schedule,
// (256,3), builtin exp2 + "s_nop 1" inside cvt_pk asm (trans-use hazard
// protection — root cause of R7/R10/R11 failures), ones-MFMA L, XCD
// head-pinning. Structural fixed point across five variants.
#define DRAINBAR() do { \
    asm volatile("s_waitcnt vmcnt(0)" ::: "memory"); \
    __builtin_amdgcn_s_barrier(); \
    asm volatile("" ::: "memory"); } while (0)

__global__ __launch_bounds__(256, 3) void k_attn(
    const unsigned short* __restrict__ Qb, const unsigned short* __restrict__ Kb,
    const unsigned short* __restrict__ Vp, unsigned short* __restrict__ Ob)
{
  const int lin = blockIdx.x;                        // 0..511
  const int xcd = lin & 7, slot = lin >> 3;          // heads pinned per XCD
  const int bh = xcd * 4 + (slot & 3);
  const int qblk = slot >> 2;                        // 0..15
  const int b = bh >> 3, h = bh & 7;

  const int tid = threadIdx.x, lane = tid & 63, wid = tid >> 6;
  const int q0 = qblk * 128 + wid * 32;
  const int r16 = lane & 15, g = lane >> 4;
  const int swz = r16 & 7;
  const unsigned short* Qh = Qb + (size_t)bh * T_ * 64;
  const unsigned short* Kh = Kb + (size_t)bh * T_ * 64;
  const unsigned short* Vh = Vp + (size_t)bh * 64 * T_;

  __shared__ unsigned short Ks[2][4096];             // [64 rows][64 elems], swizzled
  __shared__ unsigned short Vs[2][4096];

  // Q as MFMA B-frag (pre-scaled): col = lane&15 = q-row, d = g*8+i
  const bf16x8 qa00 = *(const bf16x8*)&Qh[(size_t)(q0 + r16) * 64 + g * 8];
  const bf16x8 qa01 = *(const bf16x8*)&Qh[(size_t)(q0 + r16) * 64 + 32 + g * 8];
  const bf16x8 qa10 = *(const bf16x8*)&Qh[(size_t)(q0 + 16 + r16) * 64 + g * 8];
  const bf16x8 qa11 = *(const bf16x8*)&Qh[(size_t)(q0 + 16 + r16) * 64 + 32 + g * 8];

  const f32x4 fz = {0.f, 0.f, 0.f, 0.f};
  f32x4 accA[4], accB[4];                            // O^T per q-set
#pragma unroll
  for (int eb = 0; eb < 4; ++eb) { accA[eb] = fz; accB[eb] = fz; }
  f32x4 accLA = fz, accLB = fz;                      // row-sums via ones-MFMA

  bf16x8 onesv;
#pragma unroll
  for (int i = 0; i < 8; ++i) onesv[i] = (short)0x3F80;  // bf16 1.0

  // staging: lane writes 16B at LDS linear (wid*1024B + lane*16B) [+4096B]
  // row = wid*8 + (lane>>3) [+32]; chunk pos = lane&7; source chunk = pos ^ (row&7)
  const int sb = wid * 8 + (lane >> 3);
  const int ssc = (lane & 7) ^ (lane >> 3);
  const unsigned short* kg = Kh + (size_t)sb * 64 + ssc * 8;
  const unsigned short* vg = Vh + (size_t)sb * T_ + ssc * 8;

  auto stage = [&](const unsigned short* kgp, const unsigned short* vgp, int bf) {
    gload_lds16(kgp,                   &Ks[bf][wid * 512]);
    gload_lds16(kgp + 32 * 64,         &Ks[bf][2048 + wid * 512]);
    gload_lds16(vgp,                   &Vs[bf][wid * 512]);
    gload_lds16(vgp + (size_t)32 * T_, &Vs[bf][2048 + wid * 512]);
  };

  auto compute = [&](int bf) {
#pragma unroll
    for (int sub = 0; sub < 2; ++sub) {
      const int rb = (sub * 32 + r16) * 64;
      const int c0 = (g ^ swz) << 3;
      const bf16x8 kf00 = *(const bf16x8*)&Ks[bf][rb + c0];
      const bf16x8 kf01 = *(const bf16x8*)&Ks[bf][rb + (c0 ^ 32)];
      const bf16x8 kf10 = *(const bf16x8*)&Ks[bf][rb + 1024 + c0];
      const bf16x8 kf11 = *(const bf16x8*)&Ks[bf][rb + 1024 + (c0 ^ 32)];
      // q-set A
      f32x4 s0a = __builtin_amdgcn_mfma_f32_16x16x32_bf16(kf00, qa00, fz, 0, 0, 0);
      s0a = __builtin_amdgcn_mfma_f32_16x16x32_bf16(kf01, qa01, s0a, 0, 0, 0);
      f32x4 s1a = __builtin_amdgcn_mfma_f32_16x16x32_bf16(kf10, qa00, fz, 0, 0, 0);
      s1a = __builtin_amdgcn_mfma_f32_16x16x32_bf16(kf11, qa01, s1a, 0, 0, 0);
      // q-set B
      f32x4 s0b = __builtin_amdgcn_mfma_f32_16x16x32_bf16(kf00, qa10, fz, 0, 0, 0);
      s0b = __builtin_amdgcn_mfma_f32_16x16x32_bf16(kf01, qa11, s0b, 0, 0, 0);
      f32x4 s1b = __builtin_amdgcn_mfma_f32_16x16x32_bf16(kf10, qa10, fz, 0, 0, 0);
      s1b = __builtin_amdgcn_mfma_f32_16x16x32_bf16(kf11, qa11, s1b, 0, 0, 0);

      float pa[8], pb[8];
#pragma unroll
      for (int r = 0; r < 4; ++r) {
        pa[r]     = __builtin_amdgcn_exp2f(s0a[r]);
        pa[4 + r] = __builtin_amdgcn_exp2f(s1a[r]);
        pb[r]     = __builtin_amdgcn_exp2f(s0b[r]);
        pb[4 + r] = __builtin_amdgcn_exp2f(s1b[r]);
      }
      union { bf16x8 v; unsigned u[4]; } puA, puB;
#pragma unroll
      for (int i = 0; i < 4; ++i) {
        asm("s_nop 1\n\tv_cvt_pk_bf16_f32 %0, %1, %2"
            : "=v"(puA.u[i]) : "v"(pa[2 * i]), "v"(pa[2 * i + 1]));
        asm("s_nop 1\n\tv_cvt_pk_bf16_f32 %0, %1, %2"
            : "=v"(puB.u[i]) : "v"(pb[2 * i]), "v"(pb[2 * i + 1]));
      }

#pragma unroll
      for (int eb = 0; eb < 4; ++eb) {
        const bf16x8 vf = *(const bf16x8*)&Vs[bf][(eb * 16 + r16) * 64 + (c0 ^ (sub << 5))];
        accA[eb] = __builtin_amdgcn_mfma_f32_16x16x32_bf16(vf, puA.v, accA[eb], 0, 0, 0);
        accB[eb] = __builtin_amdgcn_mfma_f32_16x16x32_bf16(vf, puB.v, accB[eb], 0, 0, 0);
      }
      accLA = __builtin_amdgcn_mfma_f32_16x16x32_bf16(onesv, puA.v, accLA, 0, 0, 0);
      accLB = __builtin_amdgcn_mfma_f32_16x16x32_bf16(onesv, puB.v, accLB, 0, 0, 0);
    }
  };

  // prologue: tile 0 into buf0, full drain
  stage(kg, vg, 0); kg += 4096; vg += 64;
  DRAINBAR();

  // main: one barrier per tile; stage(t+1) flight hidden under compute(t)
#pragma unroll 1
  for (int t = 0; t < 32; t += 2) {
    stage(kg, vg, 1); kg += 4096; vg += 64;          // tile t+1 -> buf1
    compute(0);                                      // tile t   (buf0)
    DRAINBAR();
    if (t < 30) { stage(kg, vg, 0); kg += 4096; vg += 64; }  // tile t+2 -> buf0
    compute(1);                                      // tile t+1 (buf1)
    DRAINBAR();
  }

  const float invLA = 1.0f / accLA[0];
  const float invLB = 1.0f / accLB[0];
  unsigned short* OrowA = Ob + ((size_t)(b * 2048 + q0 + r16) << 9) + h * 64 + g * 4;
  unsigned short* OrowB = Ob + ((size_t)(b * 2048 + q0 + 16 + r16) << 9) + h * 64 + g * 4;
#pragma unroll
  for (int eb = 0; eb < 4; ++eb) {
    uint2 ow;
    asm("v_cvt_pk_bf16_f32 %0, %1, %2" : "=v"(ow.x)
        : "v"(accA[eb][0] * invLA), "v"(accA[eb][1] * invLA));
    asm("v_cvt_pk_bf16_f32 %0, %1, %2" : "=v"(ow.y)
        : "v"(accA[eb][2] * invLA), "v"(accA[eb][3] * invLA));
    *(uint2*)(OrowA + eb * 16) = ow;
    asm("v_cvt_pk_bf16_f32 %0, %1, %2" : "=v"(ow.x)
        : "v"(accB[eb][0] * invLB), "v"(accB[eb][1] * invLB));
    asm("v_cvt_pk_bf16_f32 %0, %1, %2" : "=v"(ow.y)
        : "v"(accB[eb][2] * invLB), "v"(accB[eb][3] * invLB));
    *(uint2*)(OrowB + eb * 16) = ow;
  }
}

// ---------------- launch ----------------
extern "C" void kernel_launch(void* const* d_in, const int* in_sizes, int n_in,
                              void* d_out, int out_size, void* d_ws, size_t ws_size,
                              hipStream_t stream) {
  const float* x  = (const float*)d_in[0];
  const float* Wq = (const float*)d_in[1];
  const float* Wk = (const float*)d_in[2];
  const float* Wv = (const float*)d_in[3];
  const float* Wo = (const float*)d_in[4];
  const float* bo = (const float*)d_in[5];
  float* out = (float*)d_out;
  char* ws = (char*)d_ws;

  unsigned short* xb  = (unsigned short*)(ws);                 // 8 MiB
  unsigned short* Wtq = (unsigned short*)(ws + 8388608);       // 1.5 MiB
  unsigned short* Wto = (unsigned short*)(ws + 9961472);       // 0.5 MiB
  unsigned short* Qb  = (unsigned short*)(ws + 10485760);      // 8 MiB
  unsigned short* Kb  = (unsigned short*)(ws + 18874368);      // 8 MiB
  unsigned short* Vp  = (unsigned short*)(ws + 27262976);      // 8 MiB
  unsigned short* Ob  = (unsigned short*)(ws + 35651584);      // 8 MiB

  k_prep    <<<8192, 256, 0, stream>>>(x, Wq, Wk, Wv, Wo, xb, Wtq, Wto);
  k_gemm<0> <<<dim3(12, 64), 256, 0, stream>>>(xb, Wtq, Qb, Kb, Vp, nullptr, nullptr);
  k_attn    <<<512, 256, 0, stream>>>(Qb, Kb, Vp, Ob);
  k_gemm<1> <<<dim3(4, 64), 256, 0, stream>>>(Ob, Wto, nullptr, nullptr, nullptr, bo, out);
}

// Round 20
// 90.741 us; speedup vs baseline: 1.1135x; 1.0272x over previous
//
#include <hip/hip_runtime.h>
#include <stdint.h>

// Problem constants
#define B_   4
#define T_   2048
#define D_   512
#define H_   8
#define HS_  64

typedef __attribute__((ext_vector_type(8))) short bf16x8;
typedef __attribute__((ext_vector_type(4))) float f32x4;

__device__ __forceinline__ unsigned short f2bf(float f) {
  union { float f; unsigned u; } v; v.f = f;
  unsigned r = v.u + 0x7fffu + ((v.u >> 16) & 1u);   // RNE
  return (unsigned short)(r >> 16);
}

__device__ __forceinline__ void gload_lds16(const void* g, void* l) {
  __builtin_amdgcn_global_load_lds(
      (const __attribute__((address_space(1))) void*)g,
      (__attribute__((address_space(3))) void*)l,
      16, 0, 0);
}

// ---------------- fused prep: cast x, repack Wqkv, transpose Wo -------------
__global__ __launch_bounds__(256) void k_prep(
    const float* __restrict__ x,
    const float* __restrict__ Wq, const float* __restrict__ Wk,
    const float* __restrict__ Wv, const float* __restrict__ Wo,
    unsigned short* __restrict__ xb, unsigned short* __restrict__ Wtq,
    unsigned short* __restrict__ Wto)
{
  const int bid = blockIdx.x, tid = threadIdx.x;
  if (bid < 4096) {                                  // cast x: 4 floats/thread
    const int i = bid * 256 + tid;
    float4 v = ((const float4*)x)[i];
    ushort4 o;
    o.x = f2bf(v.x); o.y = f2bf(v.y); o.z = f2bf(v.z); o.w = f2bf(v.w);
    ((ushort4*)xb)[i] = o;
  } else if (bid < 7168) {                           // Wt[n][d] = Wproj[h][d][e]
    const int idx = (bid - 4096) * 256 + tid;        // < 1536*512
    const int n = idx >> 9, d = idx & 511;
    const int proj = n >> 9, c = n & 511, h = c >> 6, e = c & 63;
    const float* W = (proj == 0) ? Wq : ((proj == 1) ? Wk : Wv);
    Wtq[idx] = f2bf(W[((h << 9) + d) * 64 + e]);
  } else {                                           // Wot[n][d] = Wo[d][n]
    const int idx = (bid - 7168) * 256 + tid;        // < 512*512
    const int n = idx >> 9, d = idx & 511;
    Wto[idx] = f2bf(Wo[(d << 9) + n]);
  }
}

// ---------------- GEMM: C[M][N] = A[M][512] * Bt[N][512]^T ----------------
// This round: BK=64 tiles with the ATTN-PROVEN XOR swizzle (the [64-col,
// 8-chunk] pattern k_attn has run conflict-free for 7 rounds):
//   LDS[row][pos] = src[row][pos ^ (row&7)]  (chunk = 8 shorts, 16B)
//   read chunk c of row at pos = c ^ (row&7)
// Fixes the m97-linear-layout ~8-way ds_read_b128 bank conflict (row stride
// 64B put 16 fragment lanes on banks {0-3,16-19}) AND halves the K-loop
// barrier count (8 steps of BK=64 vs 16 of BK=32). LDS 32 KB (unchanged
// occupancy). Per-half compute (8 frags -> 16 MFMAs, twice) keeps register
// pressure at the BK=32 level. + R19's XCD-chunked bijective block swizzle.
// MODE 0: scatter bf16 into Qb [B,H,T,64] (pre-scaled by HS^-0.5*log2e),
//         Kb [B,H,T,64], Vp [B,H,64,T] k-permuted; V packed ushort4 stores.
// MODE 1: fp32 out + bias into Cout [M][512]
template<int MODE>
__global__ __launch_bounds__(256) void k_gemm(
    const unsigned short* __restrict__ A, const unsigned short* __restrict__ Bt,
    unsigned short* __restrict__ Qb, unsigned short* __restrict__ Kb,
    unsigned short* __restrict__ Vp,
    const float* __restrict__ bo, float* __restrict__ Cout)
{
  // XCD-chunked bijective remap (nwg % 8 == 0: 768 and 256)
  const int nwg = gridDim.x * gridDim.y;
  const int lin = blockIdx.y * gridDim.x + blockIdx.x;
  const int chunk = nwg >> 3;
  const int wk = (lin & 7) * chunk + (lin >> 3);
  const int m0 = (wk / gridDim.x) * 128, n0 = (wk % gridDim.x) * 128;

  __shared__ unsigned short At[128 * 64];            // [128 rows][64 cols], swizzled
  __shared__ unsigned short Bs[128 * 64];
  const int tid = threadIdx.x, lane = tid & 63, wid = tid >> 6;
  const int wm = wid >> 1, wn = wid & 1;
  const int r16 = lane & 15, g = lane >> 4;
  const int swz = r16 & 7;

  // staging lane decomposition (identical to k_attn): 8 rows x 8 chunks/wave
  const int srow = lane >> 3;                        // 0..7
  const int ssc  = (lane & 7) ^ srow;                // swizzled source chunk

  f32x4 acc[4][4];
  const f32x4 fz = {0.f, 0.f, 0.f, 0.f};
#pragma unroll
  for (int i = 0; i < 4; ++i)
#pragma unroll
    for (int j = 0; j < 4; ++j) acc[i][j] = fz;

  for (int k0 = 0; k0 < 512; k0 += 64) {
#pragma unroll
    for (int j = 0; j < 4; ++j) {                    // 4 rounds x 32 rows
      const int row = j * 32 + wid * 8 + srow;
      gload_lds16(A  + (size_t)(m0 + row) * 512 + k0 + ssc * 8,
                  &At[(j * 32 + wid * 8) * 64]);
      gload_lds16(Bt + (size_t)(n0 + row) * 512 + k0 + ssc * 8,
                  &Bs[(j * 32 + wid * 8) * 64]);
    }
    __syncthreads();
#pragma unroll
    for (int s = 0; s < 2; ++s) {                    // two 32-k halves
      bf16x8 am[4], bn[4];
#pragma unroll
      for (int mi = 0; mi < 4; ++mi)
        am[mi] = *(const bf16x8*)&At[(wm * 64 + mi * 16 + r16) * 64 + ((((s << 2) + g) ^ swz) << 3)];
#pragma unroll
      for (int ni = 0; ni < 4; ++ni)
        bn[ni] = *(const bf16x8*)&Bs[(wn * 64 + ni * 16 + r16) * 64 + ((((s << 2) + g) ^ swz) << 3)];
#pragma unroll
      for (int mi = 0; mi < 4; ++mi)
#pragma unroll
        for (int ni = 0; ni < 4; ++ni)
          acc[mi][ni] = __builtin_amdgcn_mfma_f32_16x16x32_bf16(am[mi], bn[ni], acc[mi][ni], 0, 0, 0);
    }
    __syncthreads();
  }

  const float QSC = 0.18033688f;                     // HS^-0.5 * log2(e)
#pragma unroll
  for (int mi = 0; mi < 4; ++mi) {
#pragma unroll
    for (int ni = 0; ni < 4; ++ni) {
      if (MODE == 0) {
        const int n = n0 + wn * 64 + ni * 16 + r16;
        const int proj = n >> 9, c = n & 511, h = c >> 6, e = c & 63;
        const int mbase = m0 + wm * 64 + mi * 16 + g * 4;   // + r, r=0..3
        const int b = mbase >> 11;
        if (proj == 2) {
          const int t0 = mbase & 2047;
          const int tblk = t0 >> 5;
          const int j0 = (g << 3) + ((mi & 1) << 2);
          ushort4 pv;
          pv.x = f2bf(acc[mi][ni][0]);
          pv.y = f2bf(acc[mi][ni][1]);
          pv.z = f2bf(acc[mi][ni][2]);
          pv.w = f2bf(acc[mi][ni][3]);
          *(ushort4*)&Vp[(((size_t)(b * 8 + h) << 6) + e) * 2048 + (tblk << 5) + j0] = pv;
        } else {
#pragma unroll
          for (int r = 0; r < 4; ++r) {
            const int m = mbase + r;
            const int t = m & 2047;
            const float val = acc[mi][ni][r];
            if (proj == 0)
              Qb[(((size_t)(b * 8 + h) * 2048 + t) << 6) + e] = f2bf(val * QSC);
            else
              Kb[(((size_t)(b * 8 + h) * 2048 + t) << 6) + e] = f2bf(val);
          }
        }
      } else {
#pragma unroll
        for (int r = 0; r < 4; ++r) {
          const int m = m0 + wm * 64 + mi * 16 + g * 4 + r;
          const int n = n0 + wn * 64 + ni * 16 + r16;
          Cout[(size_t)m * 512 + n] = acc[mi][ni][r] + bo[n];
        }
      }
    }
  }
}

// ---------------- flash attention (LDS-staged K/V, 2 q-sets/wave) -----------
// R13/R16 exactly (best: 45.3us attn, passing) — FROZEN. Drain schedule,
// (256,3), builtin exp2 + "s_nop 1" inside cvt_pk asm (trans-use hazard
// protection — root cause of R7/R10/R11 failures), ones-MFMA L, XCD
// head-pinning. Structural fixed point across five variants.
#define DRAINBAR() do { \
    asm volatile("s_waitcnt vmcnt(0)" ::: "memory"); \
    __builtin_amdgcn_s_barrier(); \
    asm volatile("" ::: "memory"); } while (0)

__global__ __launch_bounds__(256, 3) void k_attn(
    const unsigned short* __restrict__ Qb, const unsigned short* __restrict__ Kb,
    const unsigned short* __restrict__ Vp, unsigned short* __restrict__ Ob)
{
  const int lin = blockIdx.x;                        // 0..511
  const int xcd = lin & 7, slot = lin >> 3;          // heads pinned per XCD
  const int bh = xcd * 4 + (slot & 3);
  const int qblk = slot >> 2;                        // 0..15
  const int b = bh >> 3, h = bh & 7;

  const int tid = threadIdx.x, lane = tid & 63, wid = tid >> 6;
  const int q0 = qblk * 128 + wid * 32;
  const int r16 = lane & 15, g = lane >> 4;
  const int swz = r16 & 7;
  const unsigned short* Qh = Qb + (size_t)bh * T_ * 64;
  const unsigned short* Kh = Kb + (size_t)bh * T_ * 64;
  const unsigned short* Vh = Vp + (size_t)bh * 64 * T_;

  __shared__ unsigned short Ks[2][4096];             // [64 rows][64 elems], swizzled
  __shared__ unsigned short Vs[2][4096];

  // Q as MFMA B-frag (pre-scaled): col = lane&15 = q-row, d = g*8+i
  const bf16x8 qa00 = *(const bf16x8*)&Qh[(size_t)(q0 + r16) * 64 + g * 8];
  const bf16x8 qa01 = *(const bf16x8*)&Qh[(size_t)(q0 + r16) * 64 + 32 + g * 8];
  const bf16x8 qa10 = *(const bf16x8*)&Qh[(size_t)(q0 + 16 + r16) * 64 + g * 8];
  const bf16x8 qa11 = *(const bf16x8*)&Qh[(size_t)(q0 + 16 + r16) * 64 + 32 + g * 8];

  const f32x4 fz = {0.f, 0.f, 0.f, 0.f};
  f32x4 accA[4], accB[4];                            // O^T per q-set
#pragma unroll
  for (int eb = 0; eb < 4; ++eb) { accA[eb] = fz; accB[eb] = fz; }
  f32x4 accLA = fz, accLB = fz;                      // row-sums via ones-MFMA

  bf16x8 onesv;
#pragma unroll
  for (int i = 0; i < 8; ++i) onesv[i] = (short)0x3F80;  // bf16 1.0

  // staging: lane writes 16B at LDS linear (wid*1024B + lane*16B) [+4096B]
  // row = wid*8 + (lane>>3) [+32]; chunk pos = lane&7; source chunk = pos ^ (row&7)
  const int sb = wid * 8 + (lane >> 3);
  const int ssc = (lane & 7) ^ (lane >> 3);
  const unsigned short* kg = Kh + (size_t)sb * 64 + ssc * 8;
  const unsigned short* vg = Vh + (size_t)sb * T_ + ssc * 8;

  auto stage = [&](const unsigned short* kgp, const unsigned short* vgp, int bf) {
    gload_lds16(kgp,                   &Ks[bf][wid * 512]);
    gload_lds16(kgp + 32 * 64,         &Ks[bf][2048 + wid * 512]);
    gload_lds16(vgp,                   &Vs[bf][wid * 512]);
    gload_lds16(vgp + (size_t)32 * T_, &Vs[bf][2048 + wid * 512]);
  };

  auto compute = [&](int bf) {
#pragma unroll
    for (int sub = 0; sub < 2; ++sub) {
      const int rb = (sub * 32 + r16) * 64;
      const int c0 = (g ^ swz) << 3;
      const bf16x8 kf00 = *(const bf16x8*)&Ks[bf][rb + c0];
      const bf16x8 kf01 = *(const bf16x8*)&Ks[bf][rb + (c0 ^ 32)];
      const bf16x8 kf10 = *(const bf16x8*)&Ks[bf][rb + 1024 + c0];
      const bf16x8 kf11 = *(const bf16x8*)&Ks[bf][rb + 1024 + (c0 ^ 32)];
      // q-set A
      f32x4 s0a = __builtin_amdgcn_mfma_f32_16x16x32_bf16(kf00, qa00, fz, 0, 0, 0);
      s0a = __builtin_amdgcn_mfma_f32_16x16x32_bf16(kf01, qa01, s0a, 0, 0, 0);
      f32x4 s1a = __builtin_amdgcn_mfma_f32_16x16x32_bf16(kf10, qa00, fz, 0, 0, 0);
      s1a = __builtin_amdgcn_mfma_f32_16x16x32_bf16(kf11, qa01, s1a, 0, 0, 0);
      // q-set B
      f32x4 s0b = __builtin_amdgcn_mfma_f32_16x16x32_bf16(kf00, qa10, fz, 0, 0, 0);
      s0b = __builtin_amdgcn_mfma_f32_16x16x32_bf16(kf01, qa11, s0b, 0, 0, 0);
      f32x4 s1b = __builtin_amdgcn_mfma_f32_16x16x32_bf16(kf10, qa10, fz, 0, 0, 0);
      s1b = __builtin_amdgcn_mfma_f32_16x16x32_bf16(kf11, qa11, s1b, 0, 0, 0);

      float pa[8], pb[8];
#pragma unroll
      for (int r = 0; r < 4; ++r) {
        pa[r]     = __builtin_amdgcn_exp2f(s0a[r]);
        pa[4 + r] = __builtin_amdgcn_exp2f(s1a[r]);
        pb[r]     = __builtin_amdgcn_exp2f(s0b[r]);
        pb[4 + r] = __builtin_amdgcn_exp2f(s1b[r]);
      }
      union { bf16x8 v; unsigned u[4]; } puA, puB;
#pragma unroll
      for (int i = 0; i < 4; ++i) {
        asm("s_nop 1\n\tv_cvt_pk_bf16_f32 %0, %1, %2"
            : "=v"(puA.u[i]) : "v"(pa[2 * i]), "v"(pa[2 * i + 1]));
        asm("s_nop 1\n\tv_cvt_pk_bf16_f32 %0, %1, %2"
            : "=v"(puB.u[i]) : "v"(pb[2 * i]), "v"(pb[2 * i + 1]));
      }

#pragma unroll
      for (int eb = 0; eb < 4; ++eb) {
        const bf16x8 vf = *(const bf16x8*)&Vs[bf][(eb * 16 + r16) * 64 + (c0 ^ (sub << 5))];
        accA[eb] = __builtin_amdgcn_mfma_f32_16x16x32_bf16(vf, puA.v, accA[eb], 0, 0, 0);
        accB[eb] = __builtin_amdgcn_mfma_f32_16x16x32_bf16(vf, puB.v, accB[eb], 0, 0, 0);
      }
      accLA = __builtin_amdgcn_mfma_f32_16x16x32_bf16(onesv, puA.v, accLA, 0, 0, 0);
      accLB = __builtin_amdgcn_mfma_f32_16x16x32_bf16(onesv, puB.v, accLB, 0, 0, 0);
    }
  };

  // prologue: tile 0 into buf0, full drain
  stage(kg, vg, 0); kg += 4096; vg += 64;
  DRAINBAR();

  // main: one barrier per tile; stage(t+1) flight hidden under compute(t)
#pragma unroll 1
  for (int t = 0; t < 32; t += 2) {
    stage(kg, vg, 1); kg += 4096; vg += 64;          // tile t+1 -> buf1
    compute(0);                                      // tile t   (buf0)
    DRAINBAR();
    if (t < 30) { stage(kg, vg, 0); kg += 4096; vg += 64; }  // tile t+2 -> buf0
    compute(1);                                      // tile t+1 (buf1)
    DRAINBAR();
  }

  const float invLA = 1.0f / accLA[0];
  const float invLB = 1.0f / accLB[0];
  unsigned short* OrowA = Ob + ((size_t)(b * 2048 + q0 + r16) << 9) + h * 64 + g * 4;
  unsigned short* OrowB = Ob + ((size_t)(b * 2048 + q0 + 16 + r16) << 9) + h * 64 + g * 4;
#pragma unroll
  for (int eb = 0; eb < 4; ++eb) {
    uint2 ow;
    asm("v_cvt_pk_bf16_f32 %0, %1, %2" : "=v"(ow.x)
        : "v"(accA[eb][0] * invLA), "v"(accA[eb][1] * invLA));
    asm("v_cvt_pk_bf16_f32 %0, %1, %2" : "=v"(ow.y)
        : "v"(accA[eb][2] * invLA), "v"(accA[eb][3] * invLA));
    *(uint2*)(OrowA + eb * 16) = ow;
    asm("v_cvt_pk_bf16_f32 %0, %1, %2" : "=v"(ow.x)
        : "v"(accB[eb][0] * invLB), "v"(accB[eb][1] * invLB));
    asm("v_cvt_pk_bf16_f32 %0, %1, %2" : "=v"(ow.y)
        : "v"(accB[eb][2] * invLB), "v"(accB[eb][3] * invLB));
    *(uint2*)(OrowB + eb * 16) = ow;
  }
}

// ---------------- launch ----------------
extern "C" void kernel_launch(void* const* d_in, const int* in_sizes, int n_in,
                              void* d_out, int out_size, void* d_ws, size_t ws_size,
                              hipStream_t stream) {
  const float* x  = (const float*)d_in[0];
  const float* Wq = (const float*)d_in[1];
  const float* Wk = (const float*)d_in[2];
  const float* Wv = (const float*)d_in[3];
  const float* Wo = (const float*)d_in[4];
  const float* bo = (const float*)d_in[5];
  float* out = (float*)d_out;
  char* ws = (char*)d_ws;

  unsigned short* xb  = (unsigned short*)(ws);                 // 8 MiB
  unsigned short* Wtq = (unsigned short*)(ws + 8388608);       // 1.5 MiB
  unsigned short* Wto = (unsigned short*)(ws + 9961472);       // 0.5 MiB
  unsigned short* Qb  = (unsigned short*)(ws + 10485760);      // 8 MiB
  unsigned short* Kb  = (unsigned short*)(ws + 18874368);      // 8 MiB
  unsigned short* Vp  = (unsigned short*)(ws + 27262976);      // 8 MiB
  unsigned short* Ob  = (unsigned short*)(ws + 35651584);      // 8 MiB

  k_prep    <<<8192, 256, 0, stream>>>(x, Wq, Wk, Wv, Wo, xb, Wtq, Wto);
  k_gemm<0> <<<dim3(12, 64), 256, 0, stream>>>(xb, Wtq, Qb, Kb, Vp, nullptr, nullptr);
  k_attn    <<<512, 256, 0, stream>>>(Qb, Kb, Vp, Ob);
  k_gemm<1> <<<dim3(4, 64), 256, 0, stream>>>(Ob, Wto, nullptr, nullptr, nullptr, bo, out);
}

// Round 21
// 88.339 us; speedup vs baseline: 1.1438x; 1.0272x over previous
//
#include <hip/hip_runtime.h>
#include <stdint.h>

// Problem constants
#define B_   4
#define T_   2048
#define D_   512
#define H_   8
#define HS_  64

typedef __attribute__((ext_vector_type(8))) short bf16x8;
typedef __attribute__((ext_vector_type(4))) float f32x4;

__device__ __forceinline__ unsigned short f2bf(float f) {
  union { float f; unsigned u; } v; v.f = f;
  unsigned r = v.u + 0x7fffu + ((v.u >> 16) & 1u);   // RNE
  return (unsigned short)(r >> 16);
}

__device__ __forceinline__ void gload_lds16(const void* g, void* l) {
  __builtin_amdgcn_global_load_lds(
      (const __attribute__((address_space(1))) void*)g,
      (__attribute__((address_space(3))) void*)l,
      16, 0, 0);
}

// ---------------- fused prep: cast x + COALESCED weight transposes ----------
// R20 post-mortem: old repacks read W at 256B/2KB stride (16x overfetch,
// ~8-10us). Now: standard LDS 64x64 tile transpose ([64][65] f32 padding ->
// 2-way banks = free): float4 coalesced reads -> LDS -> column reads ->
// packed ushort4 coalesced writes. Same f2bf values, same destinations.
__global__ __launch_bounds__(256) void k_prep(
    const float* __restrict__ x,
    const float* __restrict__ Wq, const float* __restrict__ Wk,
    const float* __restrict__ Wv, const float* __restrict__ Wo,
    unsigned short* __restrict__ xb, unsigned short* __restrict__ Wtq,
    unsigned short* __restrict__ Wto)
{
  const int bid = blockIdx.x, tid = threadIdx.x;
  if (bid < 4096) {                                  // cast x: 4 floats/thread
    const int i = bid * 256 + tid;
    float4 v = ((const float4*)x)[i];
    ushort4 o;
    o.x = f2bf(v.x); o.y = f2bf(v.y); o.z = f2bf(v.z); o.w = f2bf(v.w);
    ((ushort4*)xb)[i] = o;
    return;
  }
  __shared__ float lds[64][65];
  const int r  = tid >> 4;                           // 0..15
  const int c4 = (tid & 15) << 2;                    // 0,4,..,60
  if (bid < 4288) {                                  // Wqkv: 192 tiles (3p x 8h x 8dt)
    const int t = bid - 4096;
    const int proj = t >> 6;                         // 0..2
    const int rem = t & 63;
    const int h = rem >> 3;                          // 0..7
    const int d0 = (rem & 7) << 6;                   // 0..448
    const float* W = (proj == 0) ? Wq : ((proj == 1) ? Wk : Wv);
    // read W[h][d0+row][e=c4..c4+3] coalesced (e fastest in memory)
#pragma unroll
    for (int it = 0; it < 4; ++it) {
      const int row = r + it * 16;
      const float4 v = *(const float4*)&W[((size_t)((h << 9) + d0 + row) << 6) + c4];
      lds[row][c4 + 0] = v.x; lds[row][c4 + 1] = v.y;
      lds[row][c4 + 2] = v.z; lds[row][c4 + 3] = v.w;
    }
    __syncthreads();
    // write Wtq[(proj*512 + h*64 + e)][d0 + dc] coalesced in d
#pragma unroll
    for (int it = 0; it < 4; ++it) {
      const int e = r + it * 16;
      ushort4 o;
      o.x = f2bf(lds[c4 + 0][e]);
      o.y = f2bf(lds[c4 + 1][e]);
      o.z = f2bf(lds[c4 + 2][e]);
      o.w = f2bf(lds[c4 + 3][e]);
      *(ushort4*)&Wtq[((size_t)((proj << 9) + (h << 6) + e) << 9) + d0 + c4] = o;
    }
  } else {                                           // Wo: 64 tiles (8n x 8d)
    const int t = bid - 4288;
    const int n0 = (t >> 3) << 6;
    const int d0 = (t & 7) << 6;
    // read Wo[d0+row][n0+c4..+3] coalesced (n fastest in memory)
#pragma unroll
    for (int it = 0; it < 4; ++it) {
      const int row = r + it * 16;
      const float4 v = *(const float4*)&Wo[((size_t)(d0 + row) << 9) + n0 + c4];
      lds[row][c4 + 0] = v.x; lds[row][c4 + 1] = v.y;
      lds[row][c4 + 2] = v.z; lds[row][c4 + 3] = v.w;
    }
    __syncthreads();
    // write Wto[(n0+e)][d0+dc] coalesced in d
#pragma unroll
    for (int it = 0; it < 4; ++it) {
      const int e = r + it * 16;
      ushort4 o;
      o.x = f2bf(lds[c4 + 0][e]);
      o.y = f2bf(lds[c4 + 1][e]);
      o.z = f2bf(lds[c4 + 2][e]);
      o.w = f2bf(lds[c4 + 3][e]);
      *(ushort4*)&Wto[((size_t)(n0 + e) << 9) + d0 + c4] = o;
    }
  }
}

// ---------------- GEMM: C[M][N] = A[M][512] * Bt[N][512]^T ----------------
// R20-proven form: BK=64 tiles + attn-proven XOR swizzle (conflict-free
// ds_read_b128), 8 K-steps, + XCD-chunked bijective block swizzle.
// MODE 0: scatter bf16 into Qb [B,H,T,64] (pre-scaled by HS^-0.5*log2e),
//         Kb [B,H,T,64], Vp [B,H,64,T] k-permuted; V packed ushort4 stores.
// MODE 1: fp32 out + bias into Cout [M][512]
template<int MODE>
__global__ __launch_bounds__(256) void k_gemm(
    const unsigned short* __restrict__ A, const unsigned short* __restrict__ Bt,
    unsigned short* __restrict__ Qb, unsigned short* __restrict__ Kb,
    unsigned short* __restrict__ Vp,
    const float* __restrict__ bo, float* __restrict__ Cout)
{
  // XCD-chunked bijective remap (nwg % 8 == 0: 768 and 256)
  const int nwg = gridDim.x * gridDim.y;
  const int lin = blockIdx.y * gridDim.x + blockIdx.x;
  const int chunk = nwg >> 3;
  const int wk = (lin & 7) * chunk + (lin >> 3);
  const int m0 = (wk / gridDim.x) * 128, n0 = (wk % gridDim.x) * 128;

  __shared__ unsigned short At[128 * 64];            // [128 rows][64 cols], swizzled
  __shared__ unsigned short Bs[128 * 64];
  const int tid = threadIdx.x, lane = tid & 63, wid = tid >> 6;
  const int wm = wid >> 1, wn = wid & 1;
  const int r16 = lane & 15, g = lane >> 4;
  const int swz = r16 & 7;

  const int srow = lane >> 3;                        // 0..7
  const int ssc  = (lane & 7) ^ srow;                // swizzled source chunk

  f32x4 acc[4][4];
  const f32x4 fz = {0.f, 0.f, 0.f, 0.f};
#pragma unroll
  for (int i = 0; i < 4; ++i)
#pragma unroll
    for (int j = 0; j < 4; ++j) acc[i][j] = fz;

  for (int k0 = 0; k0 < 512; k0 += 64) {
#pragma unroll
    for (int j = 0; j < 4; ++j) {                    // 4 rounds x 32 rows
      const int row = j * 32 + wid * 8 + srow;
      gload_lds16(A  + (size_t)(m0 + row) * 512 + k0 + ssc * 8,
                  &At[(j * 32 + wid * 8) * 64]);
      gload_lds16(Bt + (size_t)(n0 + row) * 512 + k0 + ssc * 8,
                  &Bs[(j * 32 + wid * 8) * 64]);
    }
    __syncthreads();
#pragma unroll
    for (int s = 0; s < 2; ++s) {                    // two 32-k halves
      bf16x8 am[4], bn[4];
#pragma unroll
      for (int mi = 0; mi < 4; ++mi)
        am[mi] = *(const bf16x8*)&At[(wm * 64 + mi * 16 + r16) * 64 + ((((s << 2) + g) ^ swz) << 3)];
#pragma unroll
      for (int ni = 0; ni < 4; ++ni)
        bn[ni] = *(const bf16x8*)&Bs[(wn * 64 + ni * 16 + r16) * 64 + ((((s << 2) + g) ^ swz) << 3)];
#pragma unroll
      for (int mi = 0; mi < 4; ++mi)
#pragma unroll
        for (int ni = 0; ni < 4; ++ni)
          acc[mi][ni] = __builtin_amdgcn_mfma_f32_16x16x32_bf16(am[mi], bn[ni], acc[mi][ni], 0, 0, 0);
    }
    __syncthreads();
  }

  const float QSC = 0.18033688f;                     // HS^-0.5 * log2(e)
#pragma unroll
  for (int mi = 0; mi < 4; ++mi) {
#pragma unroll
    for (int ni = 0; ni < 4; ++ni) {
      if (MODE == 0) {
        const int n = n0 + wn * 64 + ni * 16 + r16;
        const int proj = n >> 9, c = n & 511, h = c >> 6, e = c & 63;
        const int mbase = m0 + wm * 64 + mi * 16 + g * 4;   // + r, r=0..3
        const int b = mbase >> 11;
        if (proj == 2) {
          const int t0 = mbase & 2047;
          const int tblk = t0 >> 5;
          const int j0 = (g << 3) + ((mi & 1) << 2);
          ushort4 pv;
          pv.x = f2bf(acc[mi][ni][0]);
          pv.y = f2bf(acc[mi][ni][1]);
          pv.z = f2bf(acc[mi][ni][2]);
          pv.w = f2bf(acc[mi][ni][3]);
          *(ushort4*)&Vp[(((size_t)(b * 8 + h) << 6) + e) * 2048 + (tblk << 5) + j0] = pv;
        } else {
#pragma unroll
          for (int r = 0; r < 4; ++r) {
            const int m = mbase + r;
            const int t = m & 2047;
            const float val = acc[mi][ni][r];
            if (proj == 0)
              Qb[(((size_t)(b * 8 + h) * 2048 + t) << 6) + e] = f2bf(val * QSC);
            else
              Kb[(((size_t)(b * 8 + h) * 2048 + t) << 6) + e] = f2bf(val);
          }
        }
      } else {
#pragma unroll
        for (int r = 0; r < 4; ++r) {
          const int m = m0 + wm * 64 + mi * 16 + g * 4 + r;
          const int n = n0 + wn * 64 + ni * 16 + r16;
          Cout[(size_t)m * 512 + n] = acc[mi][ni][r] + bo[n];
        }
      }
    }
  }
}

// ---------------- flash attention (LDS-staged K/V, 2 q-sets/wave) -----------
// R13/R16 exactly (best: 45.3us attn, passing) — FROZEN. Drain schedule,
// (256,3), builtin exp2 + "s_nop 1" inside cvt_pk asm (trans-use hazard
// protection — root cause of R7/R10/R11 failures), ones-MFMA L, XCD
// head-pinning. Structural fixed point across five variants.
#define DRAINBAR() do { \
    asm volatile("s_waitcnt vmcnt(0)" ::: "memory"); \
    __builtin_amdgcn_s_barrier(); \
    asm volatile("" ::: "memory"); } while (0)

__global__ __launch_bounds__(256, 3) void k_attn(
    const unsigned short* __restrict__ Qb, const unsigned short* __restrict__ Kb,
    const unsigned short* __restrict__ Vp, unsigned short* __restrict__ Ob)
{
  const int lin = blockIdx.x;                        // 0..511
  const int xcd = lin & 7, slot = lin >> 3;          // heads pinned per XCD
  const int bh = xcd * 4 + (slot & 3);
  const int qblk = slot >> 2;                        // 0..15
  const int b = bh >> 3, h = bh & 7;

  const int tid = threadIdx.x, lane = tid & 63, wid = tid >> 6;
  const int q0 = qblk * 128 + wid * 32;
  const int r16 = lane & 15, g = lane >> 4;
  const int swz = r16 & 7;
  const unsigned short* Qh = Qb + (size_t)bh * T_ * 64;
  const unsigned short* Kh = Kb + (size_t)bh * T_ * 64;
  const unsigned short* Vh = Vp + (size_t)bh * 64 * T_;

  __shared__ unsigned short Ks[2][4096];             // [64 rows][64 elems], swizzled
  __shared__ unsigned short Vs[2][4096];

  // Q as MFMA B-frag (pre-scaled): col = lane&15 = q-row, d = g*8+i
  const bf16x8 qa00 = *(const bf16x8*)&Qh[(size_t)(q0 + r16) * 64 + g * 8];
  const bf16x8 qa01 = *(const bf16x8*)&Qh[(size_t)(q0 + r16) * 64 + 32 + g * 8];
  const bf16x8 qa10 = *(const bf16x8*)&Qh[(size_t)(q0 + 16 + r16) * 64 + g * 8];
  const bf16x8 qa11 = *(const bf16x8*)&Qh[(size_t)(q0 + 16 + r16) * 64 + 32 + g * 8];

  const f32x4 fz = {0.f, 0.f, 0.f, 0.f};
  f32x4 accA[4], accB[4];                            // O^T per q-set
#pragma unroll
  for (int eb = 0; eb < 4; ++eb) { accA[eb] = fz; accB[eb] = fz; }
  f32x4 accLA = fz, accLB = fz;                      // row-sums via ones-MFMA

  bf16x8 onesv;
#pragma unroll
  for (int i = 0; i < 8; ++i) onesv[i] = (short)0x3F80;  // bf16 1.0

  // staging: lane writes 16B at LDS linear (wid*1024B + lane*16B) [+4096B]
  // row = wid*8 + (lane>>3) [+32]; chunk pos = lane&7; source chunk = pos ^ (row&7)
  const int sb = wid * 8 + (lane >> 3);
  const int ssc = (lane & 7) ^ (lane >> 3);
  const unsigned short* kg = Kh + (size_t)sb * 64 + ssc * 8;
  const unsigned short* vg = Vh + (size_t)sb * T_ + ssc * 8;

  auto stage = [&](const unsigned short* kgp, const unsigned short* vgp, int bf) {
    gload_lds16(kgp,                   &Ks[bf][wid * 512]);
    gload_lds16(kgp + 32 * 64,         &Ks[bf][2048 + wid * 512]);
    gload_lds16(vgp,                   &Vs[bf][wid * 512]);
    gload_lds16(vgp + (size_t)32 * T_, &Vs[bf][2048 + wid * 512]);
  };

  auto compute = [&](int bf) {
#pragma unroll
    for (int sub = 0; sub < 2; ++sub) {
      const int rb = (sub * 32 + r16) * 64;
      const int c0 = (g ^ swz) << 3;
      const bf16x8 kf00 = *(const bf16x8*)&Ks[bf][rb + c0];
      const bf16x8 kf01 = *(const bf16x8*)&Ks[bf][rb + (c0 ^ 32)];
      const bf16x8 kf10 = *(const bf16x8*)&Ks[bf][rb + 1024 + c0];
      const bf16x8 kf11 = *(const bf16x8*)&Ks[bf][rb + 1024 + (c0 ^ 32)];
      // q-set A
      f32x4 s0a = __builtin_amdgcn_mfma_f32_16x16x32_bf16(kf00, qa00, fz, 0, 0, 0);
      s0a = __builtin_amdgcn_mfma_f32_16x16x32_bf16(kf01, qa01, s0a, 0, 0, 0);
      f32x4 s1a = __builtin_amdgcn_mfma_f32_16x16x32_bf16(kf10, qa00, fz, 0, 0, 0);
      s1a = __builtin_amdgcn_mfma_f32_16x16x32_bf16(kf11, qa01, s1a, 0, 0, 0);
      // q-set B
      f32x4 s0b = __builtin_amdgcn_mfma_f32_16x16x32_bf16(kf00, qa10, fz, 0, 0, 0);
      s0b = __builtin_amdgcn_mfma_f32_16x16x32_bf16(kf01, qa11, s0b, 0, 0, 0);
      f32x4 s1b = __builtin_amdgcn_mfma_f32_16x16x32_bf16(kf10, qa10, fz, 0, 0, 0);
      s1b = __builtin_amdgcn_mfma_f32_16x16x32_bf16(kf11, qa11, s1b, 0, 0, 0);

      float pa[8], pb[8];
#pragma unroll
      for (int r = 0; r < 4; ++r) {
        pa[r]     = __builtin_amdgcn_exp2f(s0a[r]);
        pa[4 + r] = __builtin_amdgcn_exp2f(s1a[r]);
        pb[r]     = __builtin_amdgcn_exp2f(s0b[r]);
        pb[4 + r] = __builtin_amdgcn_exp2f(s1b[r]);
      }
      union { bf16x8 v; unsigned u[4]; } puA, puB;
#pragma unroll
      for (int i = 0; i < 4; ++i) {
        asm("s_nop 1\n\tv_cvt_pk_bf16_f32 %0, %1, %2"
            : "=v"(puA.u[i]) : "v"(pa[2 * i]), "v"(pa[2 * i + 1]));
        asm("s_nop 1\n\tv_cvt_pk_bf16_f32 %0, %1, %2"
            : "=v"(puB.u[i]) : "v"(pb[2 * i]), "v"(pb[2 * i + 1]));
      }

#pragma unroll
      for (int eb = 0; eb < 4; ++eb) {
        const bf16x8 vf = *(const bf16x8*)&Vs[bf][(eb * 16 + r16) * 64 + (c0 ^ (sub << 5))];
        accA[eb] = __builtin_amdgcn_mfma_f32_16x16x32_bf16(vf, puA.v, accA[eb], 0, 0, 0);
        accB[eb] = __builtin_amdgcn_mfma_f32_16x16x32_bf16(vf, puB.v, accB[eb], 0, 0, 0);
      }
      accLA = __builtin_amdgcn_mfma_f32_16x16x32_bf16(onesv, puA.v, accLA, 0, 0, 0);
      accLB = __builtin_amdgcn_mfma_f32_16x16x32_bf16(onesv, puB.v, accLB, 0, 0, 0);
    }
  };

  // prologue: tile 0 into buf0, full drain
  stage(kg, vg, 0); kg += 4096; vg += 64;
  DRAINBAR();

  // main: one barrier per tile; stage(t+1) flight hidden under compute(t)
#pragma unroll 1
  for (int t = 0; t < 32; t += 2) {
    stage(kg, vg, 1); kg += 4096; vg += 64;          // tile t+1 -> buf1
    compute(0);                                      // tile t   (buf0)
    DRAINBAR();
    if (t < 30) { stage(kg, vg, 0); kg += 4096; vg += 64; }  // tile t+2 -> buf0
    compute(1);                                      // tile t+1 (buf1)
    DRAINBAR();
  }

  const float invLA = 1.0f / accLA[0];
  const float invLB = 1.0f / accLB[0];
  unsigned short* OrowA = Ob + ((size_t)(b * 2048 + q0 + r16) << 9) + h * 64 + g * 4;
  unsigned short* OrowB = Ob + ((size_t)(b * 2048 + q0 + 16 + r16) << 9) + h * 64 + g * 4;
#pragma unroll
  for (int eb = 0; eb < 4; ++eb) {
    uint2 ow;
    asm("v_cvt_pk_bf16_f32 %0, %1, %2" : "=v"(ow.x)
        : "v"(accA[eb][0] * invLA), "v"(accA[eb][1] * invLA));
    asm("v_cvt_pk_bf16_f32 %0, %1, %2" : "=v"(ow.y)
        : "v"(accA[eb][2] * invLA), "v"(accA[eb][3] * invLA));
    *(uint2*)(OrowA + eb * 16) = ow;
    asm("v_cvt_pk_bf16_f32 %0, %1, %2" : "=v"(ow.x)
        : "v"(accB[eb][0] * invLB), "v"(accB[eb][1] * invLB));
    asm("v_cvt_pk_bf16_f32 %0, %1, %2" : "=v"(ow.y)
        : "v"(accB[eb][2] * invLB), "v"(accB[eb][3] * invLB));
    *(uint2*)(OrowB + eb * 16) = ow;
  }
}

// ---------------- launch ----------------
extern "C" void kernel_launch(void* const* d_in, const int* in_sizes, int n_in,
                              void* d_out, int out_size, void* d_ws, size_t ws_size,
                              hipStream_t stream) {
  const float* x  = (const float*)d_in[0];
  const float* Wq = (const float*)d_in[1];
  const float* Wk = (const float*)d_in[2];
  const float* Wv = (const float*)d_in[3];
  const float* Wo = (const float*)d_in[4];
  const float* bo = (const float*)d_in[5];
  float* out = (float*)d_out;
  char* ws = (char*)d_ws;

  unsigned short* xb  = (unsigned short*)(ws);                 // 8 MiB
  unsigned short* Wtq = (unsigned short*)(ws + 8388608);       // 1.5 MiB
  unsigned short* Wto = (unsigned short*)(ws + 9961472);       // 0.5 MiB
  unsigned short* Qb  = (unsigned short*)(ws + 10485760);      // 8 MiB
  unsigned short* Kb  = (unsigned short*)(ws + 18874368);      // 8 MiB
  unsigned short* Vp  = (unsigned short*)(ws + 27262976);      // 8 MiB
  unsigned short* Ob  = (unsigned short*)(ws + 35651584);      // 8 MiB

  k_prep    <<<4352, 256, 0, stream>>>(x, Wq, Wk, Wv, Wo, xb, Wtq, Wto);
  k_gemm<0> <<<dim3(12, 64), 256, 0, stream>>>(xb, Wtq, Qb, Kb, Vp, nullptr, nullptr);
  k_attn    <<<512, 256, 0, stream>>>(Qb, Kb, Vp, Ob);
  k_gemm<1> <<<dim3(4, 64), 256, 0, stream>>>(Ob, Wto, nullptr, nullptr, nullptr, bo, out);
}